// Round 7
// baseline (90.310 us; speedup 1.0000x reference)
//
#include <hip/hip_runtime.h>

// Bidirectional NN-MSE via MFMA — R7: QT=1 to kill AGPR pressure.
//
//   loss = w * mean_n min_j ||p_n - g_j||^2 + (1-w) * mean_m min_i ||g_m - p_i||^2
//
// d^2 = qq - 2 q.r + rr computed inside mfma_f32_32x32x16_bf16 (K=16) with a
// 2-term bf16 split per operand (bf16 x bf16 products exact in fp32; absmax 0
// verified R2-R6). Refs = A (rows), queries = B (cols): each lane's 16 C-regs
// belong to one query; min over refs accumulates ELEMENTWISE (16 independent
// v_min3 chains, 8 min3/MFMA = provable minimum), tree-reduced once at end.
//
// R7 theory: R3/R5 evidence says the compiler moves MFMA dests/accumulators
// into AGPRs once VGPR demand nears ~100 (unified RF), adding accvgpr_read
// per min3 operand (3-5x VALU inflation). QT=1 caps live regs ~62 so
// everything stays VGPR-form; occupancy also rises (~8 waves/SIMD).

#define NPTS   16384
#define QBLK   128                // 4 waves x 32 queries, QT=1
#define QCH    (NPTS / QBLK)      // 128 query chunks
#define SSPLIT 16                 // ref splits
#define RBLK   (NPTS / SSPLIT)    // 1024 refs staged per block (32 KB LDS)
#define NB1    (2 * QCH * SSPLIT) // 4096 blocks

typedef __attribute__((ext_vector_type(8)))  __bf16 bf16x8;
typedef __attribute__((ext_vector_type(16))) float  floatx16;

union frag16 { __bf16 v[16]; uint4 q[2]; };

__device__ __forceinline__ float vmin16(floatx16 v) {
    float a = fminf(fminf(v[0], v[1]), v[2]);
    float b = fminf(fminf(v[3], v[4]), v[5]);
    float c = fminf(fminf(v[6], v[7]), v[8]);
    float d = fminf(fminf(v[9], v[10]), v[11]);
    float e = fminf(fminf(v[12], v[13]), fminf(v[14], v[15]));
    return fminf(fminf(fminf(a, b), fminf(c, d)), e);
}

__global__ __launch_bounds__(256) void nn_part_kernel(
    const float* __restrict__ pred, const float* __restrict__ gt,
    float* __restrict__ partial, float* __restrict__ out)
{
    const int bx   = blockIdx.x;           // 0..NB1-1
    const int dir  = bx >> 11;             // 0: Q=pred,R=gt ; 1: Q=gt,R=pred
    const int qc   = (bx & 2047) >> 4;     // 0..127
    const int s    = bx & 15;              // 0..15
    const int tid  = threadIdx.x;
    const int lane = tid & 63;
    const int wave = tid >> 6;
    const int lid  = lane & 31;
    const int half = lane >> 5;

    if (bx == 0 && tid == 0) out[0] = 0.0f;   // replaces memset launch

    const float* __restrict__ Q = dir ? gt : pred;
    const float* __restrict__ R = dir ? pred : gt;

    __shared__ uint4 ldsA[RBLK * 2];       // [tile][half][lid], 32 KB

    // ---- stage ref A-fragments into LDS ----
    const int rbase = s * RBLK;
    for (int j = tid; j < RBLK; j += 256) {
        const float x = R[(rbase + j) * 3 + 0];
        const float y = R[(rbase + j) * 3 + 1];
        const float z = R[(rbase + j) * 3 + 2];
        const float rr = x * x + y * y + z * z;
        const __bf16 xh = (__bf16)x, yh = (__bf16)y, zh = (__bf16)z;
        const __bf16 xl = (__bf16)(x - (float)xh);
        const __bf16 yl = (__bf16)(y - (float)yh);
        const __bf16 zl = (__bf16)(z - (float)zh);
        const __bf16 rh = (__bf16)rr;
        const __bf16 rl = (__bf16)(rr - (float)rh);
        const __bf16 one = (__bf16)1.0f;
        frag16 A;
        A.v[0]  = (__bf16)(-2.0f * (float)xh); A.v[1]  = A.v[0];
        A.v[2]  = (__bf16)(-2.0f * (float)xl); A.v[3]  = A.v[2];
        A.v[4]  = (__bf16)(-2.0f * (float)yh); A.v[5]  = A.v[4];
        A.v[6]  = (__bf16)(-2.0f * (float)yl); A.v[7]  = A.v[6];
        A.v[8]  = (__bf16)(-2.0f * (float)zh); A.v[9]  = A.v[8];
        A.v[10] = (__bf16)(-2.0f * (float)zl); A.v[11] = A.v[10];
        A.v[12] = rh;  A.v[13] = rl;  A.v[14] = one;  A.v[15] = one;
        const int tile = j >> 5, l = j & 31;
        ldsA[tile * 64 + l]      = A.q[0];   // k = 0..7
        ldsA[tile * 64 + 32 + l] = A.q[1];   // k = 8..15
    }

    // ---- query B-fragment in registers (one 32-query tile per wave) ----
    const int qbase = qc * QBLK + wave * 32;
    bf16x8 bq;
    {
        const int p = qbase + lid;
        const float x = Q[p * 3 + 0], y = Q[p * 3 + 1], z = Q[p * 3 + 2];
        const float qq = x * x + y * y + z * z;
        const __bf16 xh = (__bf16)x, yh = (__bf16)y, zh = (__bf16)z;
        const __bf16 xl = (__bf16)(x - (float)xh);
        const __bf16 yl = (__bf16)(y - (float)yh);
        const __bf16 zl = (__bf16)(z - (float)zh);
        const __bf16 qh = (__bf16)qq;
        const __bf16 ql = (__bf16)(qq - (float)qh);
        const __bf16 one = (__bf16)1.0f;
        frag16 B;
        B.v[0] = xh;  B.v[1]  = xl;  B.v[2]  = xh;  B.v[3]  = xl;
        B.v[4] = yh;  B.v[5]  = yl;  B.v[6]  = yh;  B.v[7]  = yl;
        B.v[8] = zh;  B.v[9]  = zl;  B.v[10] = zh;  B.v[11] = zl;
        B.v[12] = one; B.v[13] = one; B.v[14] = qh;  B.v[15] = ql;
        bq = __builtin_bit_cast(bf16x8, B.q[half]);
    }

    floatx16 zero;
#pragma unroll
    for (int k = 0; k < 16; ++k) zero[k] = 0.0f;
    floatx16 mnv;
#pragma unroll
    for (int k = 0; k < 16; ++k) mnv[k] = 3.4e38f;

    __syncthreads();

    // ---- hot loop: LDS-only, 2 ref tiles per iteration ----
#pragma unroll 2
    for (int t = 0; t < RBLK / 32; t += 2) {
        const bf16x8 a0 = __builtin_bit_cast(bf16x8, ldsA[t * 64 + half * 32 + lid]);
        const bf16x8 a1 = __builtin_bit_cast(bf16x8, ldsA[(t + 1) * 64 + half * 32 + lid]);
        floatx16 d0 = __builtin_amdgcn_mfma_f32_32x32x16_bf16(a0, bq, zero, 0, 0, 0);
        floatx16 d1 = __builtin_amdgcn_mfma_f32_32x32x16_bf16(a1, bq, zero, 0, 0, 0);
#pragma unroll
        for (int k = 0; k < 16; ++k)       // 16 independent v_min3 chains
            mnv[k] = fminf(fminf(mnv[k], d0[k]), d1[k]);
    }

    // ---- tail: in-lane tree + one shuffle, plain coalesced store ----
    float v = vmin16(mnv);
    v = fminf(v, __shfl_xor(v, 32));
    if (half == 0) {
        float* pout = partial + ((size_t)((dir * QCH + qc) * SSPLIT + s)) * QBLK
                    + wave * 32;
        pout[lid] = v;
    }
}

// Combine: min over the SSPLIT ref-splits per query, weighted sum into out.
__global__ __launch_bounds__(QBLK) void nn_combine_kernel(
    const float* __restrict__ partial, const float* __restrict__ weight,
    float* __restrict__ out)
{
    const int b   = blockIdx.x;        // 0..2*QCH-1
    const int dir = b >> 7;
    const int qc  = b & 127;
    const int t   = threadIdx.x;       // 0..127

    const float* p = partial + ((size_t)((dir * QCH + qc) * SSPLIT)) * QBLK;
    float v = p[t];
#pragma unroll
    for (int s = 1; s < SSPLIT; ++s)
        v = fminf(v, p[s * QBLK + t]);

    for (int off = 32; off; off >>= 1) v += __shfl_down(v, off);
    __shared__ float ws[2];
    if ((t & 63) == 0) ws[t >> 6] = v;
    __syncthreads();
    if (t == 0) {
        const float sum = ws[0] + ws[1];
        const float wgt = weight[0];
        const float scale = (dir ? (1.0f - wgt) : wgt) / (3.0f * (float)NPTS);
        atomicAdd(out, sum * scale);
    }
}

extern "C" void kernel_launch(void* const* d_in, const int* in_sizes, int n_in,
                              void* d_out, int out_size, void* d_ws, size_t ws_size,
                              hipStream_t stream) {
    const float* pred   = (const float*)d_in[0];
    const float* gt     = (const float*)d_in[1];
    const float* weight = (const float*)d_in[2];
    float* partial = (float*)d_ws;     // 2*QCH*SSPLIT*QBLK floats = 2 MB

    nn_part_kernel<<<NB1, 256, 0, stream>>>(pred, gt, partial, (float*)d_out);
    nn_combine_kernel<<<2 * QCH, QBLK, 0, stream>>>(partial, weight, (float*)d_out);
}

// Round 8
// 86.395 us; speedup vs baseline: 1.0453x; 1.0453x over previous
//
#include <hip/hip_runtime.h>

// Bidirectional NN-MSE via MFMA — R8: prep-kernel + global_load_lds DMA staging.
//
//   loss = w * mean_n min_j ||p_n - g_j||^2 + (1-w) * mean_m min_i ||g_m - p_i||^2
//
// d^2 = qq - 2 q.r + rr computed inside mfma_f32_32x32x16_bf16 (K=16) with a
// 2-term bf16 split per operand (exact bf16xbf16 products; absmax 0 R2-R7).
// Refs = A (rows), queries = B (cols); elementwise min3 accumulation
// (8 min3 per MFMA = provable floor), tree-reduced once per wave.
//
// R8 delta vs R6 (hot loop identical): fragment building moved to a one-time
// prep kernel (pre-swizzled [tile][half][lid] uint4 stream in ws); nn_part
// stages A-fragments via __builtin_amdgcn_global_load_lds width=16 (8 DMA
// instrs/thread, no VALU, no VGPR round-trip). Tests the theory that the
// fat conversion prologue caused the ~75% stall fraction.

#define NPTS   16384
#define QT     2                  // query tiles (32 cols) per wave
#define QBLK   (4 * QT * 32)      // 256 queries per block
#define QCH    (NPTS / QBLK)      // 64 query chunks
#define SSPLIT 16                 // ref splits
#define RBLK   (NPTS / SSPLIT)    // 1024 refs staged per block (32 KB LDS)
#define NB1    (2 * QCH * SSPLIT) // 2048 blocks

typedef __attribute__((ext_vector_type(8)))  __bf16 bf16x8;
typedef __attribute__((ext_vector_type(16))) float  floatx16;

union frag16 { __bf16 v[16]; uint4 q[2]; };

__device__ __forceinline__ float vmin16(floatx16 v) {
    float a = fminf(fminf(v[0], v[1]), v[2]);
    float b = fminf(fminf(v[3], v[4]), v[5]);
    float c = fminf(fminf(v[6], v[7]), v[8]);
    float d = fminf(fminf(v[9], v[10]), v[11]);
    float e = fminf(fminf(v[12], v[13]), fminf(v[14], v[15]));
    return fminf(fminf(fminf(a, b), fminf(c, d)), e);
}

__device__ __forceinline__ void load_lds16(const uint4* g, uint4* l) {
    __builtin_amdgcn_global_load_lds(
        (const __attribute__((address_space(1))) void*)g,
        (__attribute__((address_space(3))) void*)l, 16, 0, 0);
}

// One thread per (role, point): builds A-form (ref) and B-form (query)
// fragments. A-form is written PRE-SWIZZLED into the LDS image order:
// uint4 index g = (p>>5)*64 + half*32 + (p&31)  -> any aligned 1024-point
// range is a contiguous uint4 stream, DMA-able lane-contiguously.
__global__ __launch_bounds__(256) void prep_kernel(
    const float* __restrict__ pred, const float* __restrict__ gt,
    uint4* __restrict__ aform, uint4* __restrict__ bform,
    float* __restrict__ out)
{
    const int i = blockIdx.x * 256 + threadIdx.x;   // 0 .. 2*NPTS-1
    if (i == 0) out[0] = 0.0f;
    const int role = (i < NPTS) ? 0 : 1;            // 0=pred, 1=gt
    const int p = i - role * NPTS;
    const float* __restrict__ src = role ? gt : pred;

    const float x = src[p * 3 + 0], y = src[p * 3 + 1], z = src[p * 3 + 2];
    const float nn = x * x + y * y + z * z;
    const __bf16 xh = (__bf16)x, yh = (__bf16)y, zh = (__bf16)z;
    const __bf16 xl = (__bf16)(x - (float)xh);
    const __bf16 yl = (__bf16)(y - (float)yh);
    const __bf16 zl = (__bf16)(z - (float)zh);
    const __bf16 nh = (__bf16)nn;
    const __bf16 nl = (__bf16)(nn - (float)nh);
    const __bf16 one = (__bf16)1.0f;

    frag16 A;
    A.v[0]  = (__bf16)(-2.0f * (float)xh); A.v[1]  = A.v[0];
    A.v[2]  = (__bf16)(-2.0f * (float)xl); A.v[3]  = A.v[2];
    A.v[4]  = (__bf16)(-2.0f * (float)yh); A.v[5]  = A.v[4];
    A.v[6]  = (__bf16)(-2.0f * (float)yl); A.v[7]  = A.v[6];
    A.v[8]  = (__bf16)(-2.0f * (float)zh); A.v[9]  = A.v[8];
    A.v[10] = (__bf16)(-2.0f * (float)zl); A.v[11] = A.v[10];
    A.v[12] = nh;  A.v[13] = nl;  A.v[14] = one;  A.v[15] = one;

    frag16 B;
    B.v[0] = xh;  B.v[1]  = xl;  B.v[2]  = xh;  B.v[3]  = xl;
    B.v[4] = yh;  B.v[5]  = yl;  B.v[6]  = yh;  B.v[7]  = yl;
    B.v[8] = zh;  B.v[9]  = zl;  B.v[10] = zh;  B.v[11] = zl;
    B.v[12] = one; B.v[13] = one; B.v[14] = nh;  B.v[15] = nl;

    // A: pre-swizzled LDS-image order
    uint4* da = aform + (size_t)role * (NPTS * 2)
              + ((p >> 5) * 64 + (p & 31));
    da[0]  = A.q[0];        // half 0 (k=0..7)  at +0
    da[32] = A.q[1];        // half 1 (k=8..15) at +32
    // B: per-point [2] layout
    uint4* db = bform + (size_t)role * (NPTS * 2) + p * 2;
    db[0] = B.q[0];
    db[1] = B.q[1];
}

__global__ __launch_bounds__(256) void nn_part_kernel(
    const uint4* __restrict__ aform, const uint4* __restrict__ bform,
    float* __restrict__ partial)
{
    const int bx   = blockIdx.x;           // 0..NB1-1
    const int dir  = bx >> 10;             // 0: Q=pred,R=gt ; 1: Q=gt,R=pred
    const int qc   = (bx & 1023) >> 4;     // 0..63
    const int s    = bx & 15;              // 0..15
    const int tid  = threadIdx.x;
    const int lane = tid & 63;
    const int wave = tid >> 6;
    const int lid  = lane & 31;
    const int half = lane >> 5;

    // dir 0: queries=pred(B-form role 0), refs=gt(A-form role 1); dir 1 swapped
    const uint4* __restrict__ Aref = aform + (size_t)(dir ? 0 : 1) * (NPTS * 2);
    const uint4* __restrict__ Bqry = bform + (size_t)(dir ? 1 : 0) * (NPTS * 2);

    __shared__ uint4 ldsA[RBLK * 2];       // [tile][half][lid], 32 KB

    // ---- DMA-stage ref A-fragments: 8 x global_load_lds_dwordx4 / thread ----
    const uint4* gsrc = Aref + (size_t)s * (RBLK * 2);
#pragma unroll
    for (int i = 0; i < 8; ++i) {
        const int idx = i * 256 + wave * 64;          // wave-uniform
        load_lds16(gsrc + idx + lane, &ldsA[idx]);    // dest: base + lane*16
    }

    // ---- query B-fragments (prebuilt, 16 B/lane) ----
    const int qbase = qc * QBLK + wave * (QT * 32);
    bf16x8 bq[QT];
#pragma unroll
    for (int qt = 0; qt < QT; ++qt) {
        const int p = qbase + qt * 32 + lid;
        bq[qt] = __builtin_bit_cast(bf16x8, Bqry[p * 2 + half]);
    }

    floatx16 zero;
#pragma unroll
    for (int k = 0; k < 16; ++k) zero[k] = 0.0f;
    floatx16 mnv[QT];
#pragma unroll
    for (int qt = 0; qt < QT; ++qt)
#pragma unroll
        for (int k = 0; k < 16; ++k) mnv[qt][k] = 3.4e38f;

    __syncthreads();   // drains vmcnt (global_load_lds) + lgkmcnt

    // ---- hot loop: LDS-only, 2 ref tiles x QT MFMAs per iteration ----
#pragma unroll 2
    for (int t = 0; t < RBLK / 32; t += 2) {
        const bf16x8 a0 = __builtin_bit_cast(bf16x8, ldsA[t * 64 + half * 32 + lid]);
        const bf16x8 a1 = __builtin_bit_cast(bf16x8, ldsA[(t + 1) * 64 + half * 32 + lid]);
#pragma unroll
        for (int qt = 0; qt < QT; ++qt) {
            floatx16 d0 = __builtin_amdgcn_mfma_f32_32x32x16_bf16(a0, bq[qt], zero, 0, 0, 0);
            floatx16 d1 = __builtin_amdgcn_mfma_f32_32x32x16_bf16(a1, bq[qt], zero, 0, 0, 0);
#pragma unroll
            for (int k = 0; k < 16; ++k)   // 16 independent v_min3 chains
                mnv[qt][k] = fminf(fminf(mnv[qt][k], d0[k]), d1[k]);
        }
    }

    // ---- tail: in-lane tree + one shuffle, plain coalesced store ----
    float* pout = partial + ((size_t)((dir * QCH + qc) * SSPLIT + s)) * QBLK
                + wave * (QT * 32);
#pragma unroll
    for (int qt = 0; qt < QT; ++qt) {
        float v = vmin16(mnv[qt]);
        v = fminf(v, __shfl_xor(v, 32));
        if (half == 0) pout[qt * 32 + lid] = v;
    }
}

// Combine: min over the SSPLIT ref-splits per query, weighted sum into out.
__global__ __launch_bounds__(256) void nn_combine_kernel(
    const float* __restrict__ partial, const float* __restrict__ weight,
    float* __restrict__ out)
{
    const int b   = blockIdx.x;        // 0..127 : dir = b>>6, qc = b&63
    const int dir = b >> 6;
    const int qc  = b & 63;
    const int t   = threadIdx.x;

    const float* p = partial + ((size_t)((dir * QCH + qc) * SSPLIT)) * QBLK;
    float v = p[t];
#pragma unroll
    for (int s = 1; s < SSPLIT; ++s)
        v = fminf(v, p[s * QBLK + t]);

    for (int off = 32; off; off >>= 1) v += __shfl_down(v, off);
    __shared__ float ws[4];
    if ((t & 63) == 0) ws[t >> 6] = v;
    __syncthreads();
    if (t == 0) {
        const float sum = ws[0] + ws[1] + ws[2] + ws[3];
        const float wgt = weight[0];
        const float scale = (dir ? (1.0f - wgt) : wgt) / (3.0f * (float)NPTS);
        atomicAdd(out, sum * scale);
    }
}

extern "C" void kernel_launch(void* const* d_in, const int* in_sizes, int n_in,
                              void* d_out, int out_size, void* d_ws, size_t ws_size,
                              hipStream_t stream) {
    const float* pred   = (const float*)d_in[0];
    const float* gt     = (const float*)d_in[1];
    const float* weight = (const float*)d_in[2];

    // ws: [partial 2 MB][aform 1 MB][bform 1 MB]
    float* partial = (float*)d_ws;                       // 2*QCH*SSPLIT*QBLK f32
    uint4* aform = (uint4*)((char*)d_ws + (size_t)2 * QCH * SSPLIT * QBLK * 4);
    uint4* bform = aform + (size_t)2 * NPTS * 2;

    prep_kernel<<<2 * NPTS / 256, 256, 0, stream>>>(pred, gt, aform, bform,
                                                    (float*)d_out);
    nn_part_kernel<<<NB1, 256, 0, stream>>>(aform, bform, partial);
    nn_combine_kernel<<<2 * QCH, 256, 0, stream>>>(partial, weight, (float*)d_out);
}

// Round 9
// 85.010 us; speedup vs baseline: 1.0623x; 1.0163x over previous
//
#include <hip/hip_runtime.h>

// Bidirectional NN-MSE via MFMA — R9: NO LDS, NO BARRIER. Stream pre-swizzled
// A-fragments straight from global/L2 into MFMA operands.
//
//   loss = w * mean_n min_j ||p_n - g_j||^2 + (1-w) * mean_m min_i ||g_m - p_i||^2
//
// d^2 = qq - 2 q.r + rr computed inside mfma_f32_32x32x16_bf16 (K=16) with a
// 2-term bf16 split per operand (exact bf16xbf16 products; absmax 0 R2-R8).
// Refs = A (rows), queries = B (cols); elementwise min3 accumulation
// (8 min3 per MFMA pair-merge = provable VALU floor), tree-reduced per wave.
//
// R9 rationale: every LDS+barrier variant (R4/R6/R7/R8) sits at ~33 us vs a
// ~3.4 us VALU floor; R1's barrier-free global-load kernel sustained 87%
// VALUBusy. The stage->syncthreads->consume structure is the stall invariant.
// Here each wave's ref loads are coalesced 1 KB global_load_dwordx4 from an
// L2-hot stream (<=512 KB/XCD), vmcnt-pipelined by the compiler, no barrier.

#define NPTS   16384
#define QT     2                  // query tiles (32 cols) per wave
#define QBLK   (4 * QT * 32)      // 256 queries per block
#define QCH    (NPTS / QBLK)      // 64 query chunks
#define SSPLIT 16                 // ref splits
#define RBLK   (NPTS / SSPLIT)    // 1024 refs streamed per block
#define NB1    (2 * QCH * SSPLIT) // 2048 blocks

typedef __attribute__((ext_vector_type(8)))  __bf16 bf16x8;
typedef __attribute__((ext_vector_type(16))) float  floatx16;

union frag16 { __bf16 v[16]; uint4 q[2]; };

__device__ __forceinline__ float vmin16(floatx16 v) {
    float a = fminf(fminf(v[0], v[1]), v[2]);
    float b = fminf(fminf(v[3], v[4]), v[5]);
    float c = fminf(fminf(v[6], v[7]), v[8]);
    float d = fminf(fminf(v[9], v[10]), v[11]);
    float e = fminf(fminf(v[12], v[13]), fminf(v[14], v[15]));
    return fminf(fminf(fminf(a, b), fminf(c, d)), e);
}

// One thread per (role, point): builds A-form (ref) and B-form (query)
// fragments. A-form is written PRE-SWIZZLED in MFMA wave order: uint4 index
// (p>>5)*64 + half*32 + (p&31) -> each wave's tile read is one contiguous,
// perfectly-coalesced 1 KB global_load_dwordx4 burst.
__global__ __launch_bounds__(256) void prep_kernel(
    const float* __restrict__ pred, const float* __restrict__ gt,
    uint4* __restrict__ aform, uint4* __restrict__ bform,
    float* __restrict__ out)
{
    const int i = blockIdx.x * 256 + threadIdx.x;   // 0 .. 2*NPTS-1
    if (i == 0) out[0] = 0.0f;
    const int role = (i < NPTS) ? 0 : 1;            // 0=pred, 1=gt
    const int p = i - role * NPTS;
    const float* __restrict__ src = role ? gt : pred;

    const float x = src[p * 3 + 0], y = src[p * 3 + 1], z = src[p * 3 + 2];
    const float nn = x * x + y * y + z * z;
    const __bf16 xh = (__bf16)x, yh = (__bf16)y, zh = (__bf16)z;
    const __bf16 xl = (__bf16)(x - (float)xh);
    const __bf16 yl = (__bf16)(y - (float)yh);
    const __bf16 zl = (__bf16)(z - (float)zh);
    const __bf16 nh = (__bf16)nn;
    const __bf16 nl = (__bf16)(nn - (float)nh);
    const __bf16 one = (__bf16)1.0f;

    frag16 A;
    A.v[0]  = (__bf16)(-2.0f * (float)xh); A.v[1]  = A.v[0];
    A.v[2]  = (__bf16)(-2.0f * (float)xl); A.v[3]  = A.v[2];
    A.v[4]  = (__bf16)(-2.0f * (float)yh); A.v[5]  = A.v[4];
    A.v[6]  = (__bf16)(-2.0f * (float)yl); A.v[7]  = A.v[6];
    A.v[8]  = (__bf16)(-2.0f * (float)zh); A.v[9]  = A.v[8];
    A.v[10] = (__bf16)(-2.0f * (float)zl); A.v[11] = A.v[10];
    A.v[12] = nh;  A.v[13] = nl;  A.v[14] = one;  A.v[15] = one;

    frag16 B;
    B.v[0] = xh;  B.v[1]  = xl;  B.v[2]  = xh;  B.v[3]  = xl;
    B.v[4] = yh;  B.v[5]  = yl;  B.v[6]  = yh;  B.v[7]  = yl;
    B.v[8] = zh;  B.v[9]  = zl;  B.v[10] = zh;  B.v[11] = zl;
    B.v[12] = one; B.v[13] = one; B.v[14] = nh;  B.v[15] = nl;

    uint4* da = aform + (size_t)role * (NPTS * 2)
              + ((p >> 5) * 64 + (p & 31));
    da[0]  = A.q[0];        // half 0 (k=0..7)  at +0
    da[32] = A.q[1];        // half 1 (k=8..15) at +32
    uint4* db = bform + (size_t)role * (NPTS * 2) + p * 2;
    db[0] = B.q[0];
    db[1] = B.q[1];
}

__global__ __launch_bounds__(256) void nn_part_kernel(
    const uint4* __restrict__ aform, const uint4* __restrict__ bform,
    float* __restrict__ partial)
{
    const int bx   = blockIdx.x;           // 0..NB1-1
    const int dir  = bx >> 10;             // 0: Q=pred,R=gt ; 1: Q=gt,R=pred
    const int qc   = (bx & 1023) >> 4;     // 0..63
    const int s    = bx & 15;              // 0..15
    const int tid  = threadIdx.x;
    const int lane = tid & 63;
    const int wave = tid >> 6;
    const int lid  = lane & 31;
    const int half = lane >> 5;

    // dir 0: queries=pred(role 0), refs=gt(role 1); dir 1 swapped
    const uint4* __restrict__ Aref = aform + (size_t)(dir ? 0 : 1) * (NPTS * 2);
    const uint4* __restrict__ Bqry = bform + (size_t)(dir ? 1 : 0) * (NPTS * 2);

    // ---- query B-fragments (prebuilt, 16 B/lane) ----
    const int qbase = qc * QBLK + wave * (QT * 32);
    bf16x8 bq[QT];
#pragma unroll
    for (int qt = 0; qt < QT; ++qt) {
        const int p = qbase + qt * 32 + lid;
        bq[qt] = __builtin_bit_cast(bf16x8, Bqry[p * 2 + half]);
    }

    floatx16 zero;
#pragma unroll
    for (int k = 0; k < 16; ++k) zero[k] = 0.0f;
    floatx16 mnv[QT];
#pragma unroll
    for (int qt = 0; qt < QT; ++qt)
#pragma unroll
        for (int k = 0; k < 16; ++k) mnv[qt][k] = 3.4e38f;

    // ---- hot loop: stream A-frags from L2, no LDS, no barrier ----
    // per wave-iteration: 2 coalesced 1 KB global_load_dwordx4 bursts,
    // 4 MFMA, 32 v_min3. unroll 4 -> 8 loads in flight (vmcnt-pipelined).
    const uint4* gp = Aref + (size_t)s * (RBLK * 2) + half * 32 + lid;
#pragma unroll 4
    for (int t = 0; t < RBLK / 32; t += 2) {
        const bf16x8 a0 = __builtin_bit_cast(bf16x8, gp[t * 64]);
        const bf16x8 a1 = __builtin_bit_cast(bf16x8, gp[t * 64 + 64]);
#pragma unroll
        for (int qt = 0; qt < QT; ++qt) {
            floatx16 d0 = __builtin_amdgcn_mfma_f32_32x32x16_bf16(a0, bq[qt], zero, 0, 0, 0);
            floatx16 d1 = __builtin_amdgcn_mfma_f32_32x32x16_bf16(a1, bq[qt], zero, 0, 0, 0);
#pragma unroll
            for (int k = 0; k < 16; ++k)   // 16 independent v_min3 chains
                mnv[qt][k] = fminf(fminf(mnv[qt][k], d0[k]), d1[k]);
        }
    }

    // ---- tail: in-lane tree + one shuffle, plain coalesced store ----
    float* pout = partial + ((size_t)((dir * QCH + qc) * SSPLIT + s)) * QBLK
                + wave * (QT * 32);
#pragma unroll
    for (int qt = 0; qt < QT; ++qt) {
        float v = vmin16(mnv[qt]);
        v = fminf(v, __shfl_xor(v, 32));
        if (half == 0) pout[qt * 32 + lid] = v;
    }
}

// Combine: min over the SSPLIT ref-splits per query, weighted sum into out.
__global__ __launch_bounds__(256) void nn_combine_kernel(
    const float* __restrict__ partial, const float* __restrict__ weight,
    float* __restrict__ out)
{
    const int b   = blockIdx.x;        // 0..127 : dir = b>>6, qc = b&63
    const int dir = b >> 6;
    const int qc  = b & 63;
    const int t   = threadIdx.x;

    const float* p = partial + ((size_t)((dir * QCH + qc) * SSPLIT)) * QBLK;
    float v = p[t];
#pragma unroll
    for (int s = 1; s < SSPLIT; ++s)
        v = fminf(v, p[s * QBLK + t]);

    for (int off = 32; off; off >>= 1) v += __shfl_down(v, off);
    __shared__ float ws[4];
    if ((t & 63) == 0) ws[t >> 6] = v;
    __syncthreads();
    if (t == 0) {
        const float sum = ws[0] + ws[1] + ws[2] + ws[3];
        const float wgt = weight[0];
        const float scale = (dir ? (1.0f - wgt) : wgt) / (3.0f * (float)NPTS);
        atomicAdd(out, sum * scale);
    }
}

extern "C" void kernel_launch(void* const* d_in, const int* in_sizes, int n_in,
                              void* d_out, int out_size, void* d_ws, size_t ws_size,
                              hipStream_t stream) {
    const float* pred   = (const float*)d_in[0];
    const float* gt     = (const float*)d_in[1];
    const float* weight = (const float*)d_in[2];

    // ws: [partial 2 MB][aform 1 MB][bform 1 MB]
    float* partial = (float*)d_ws;                       // 2*QCH*SSPLIT*QBLK f32
    uint4* aform = (uint4*)((char*)d_ws + (size_t)2 * QCH * SSPLIT * QBLK * 4);
    uint4* bform = aform + (size_t)2 * NPTS * 2;

    prep_kernel<<<2 * NPTS / 256, 256, 0, stream>>>(pred, gt, aform, bform,
                                                    (float*)d_out);
    nn_part_kernel<<<NB1, 256, 0, stream>>>(aform, bform, partial);
    nn_combine_kernel<<<2 * QCH, 256, 0, stream>>>(partial, weight, (float*)d_out);
}